// Round 2
// baseline (238.788 us; speedup 1.0000x reference)
//
#include <hip/hip_runtime.h>

// B=64, C=64, H=32, P=496, HK=560, K padded to 576 (9 chunks of 64).
#define NB 64
#define NC 64
#define NH 32
#define HK 560
#define KPAD 576

typedef __bf16 bf16x8 __attribute__((ext_vector_type(8)));
typedef float f32x4 __attribute__((ext_vector_type(4)));

// One block per (c,i) group: GEMM [64 x 576] x [576 x 32], feat built in-register.
__global__ __launch_bounds__(256, 4) void hconv_kernel(
    const float* __restrict__ x, const float* __restrict__ w,
    const int* __restrict__ idx_a, const int* __restrict__ idx_b,
    float* __restrict__ out)
{
    // x rows + sentinels: [32]=1.0 (identity terms), [33]=0.0 (K-pad)
    __shared__ float s_x[NB][34];                               // 8704 B
    __shared__ __align__(16) unsigned s_lut[KPAD];              // 2304 B
    __shared__ __align__(16) unsigned short s_wT[2][32][72];    // 9216 B dbuf
    // total 20224 B -> ~7-8 blocks/CU

    const int t = threadIdx.x;
    const int g = blockIdx.x;           // 0..2047
    const int c = g >> 5, i = g & 31;

    // ---- stage x rows: 64 rows x 32 floats, float4-coalesced
    {
        const int row = t >> 3;                 // 0..31
        const int c4 = (t & 7) * 4;
        const float* xr = x + (((size_t)row * NC + c) * NH + i) * NH;
        const float* xr2 = xr + (size_t)32 * NC * NH * NH;   // row + 32
        float4 v = *(const float4*)(xr + c4);
        float4 v2 = *(const float4*)(xr2 + c4);
        s_x[row][c4] = v.x;  s_x[row][c4 + 1] = v.y;
        s_x[row][c4 + 2] = v.z; s_x[row][c4 + 3] = v.w;
        s_x[row + 32][c4] = v2.x;  s_x[row + 32][c4 + 1] = v2.y;
        s_x[row + 32][c4 + 2] = v2.z; s_x[row + 32][c4 + 3] = v2.w;
        if ((t & 7) == 0) {
            s_x[row][32] = 1.0f;      s_x[row][33] = 0.0f;
            s_x[row + 32][32] = 1.0f; s_x[row + 32][33] = 0.0f;
        }
    }

    // ---- pair LUT: feat[k] = x[pa]*x[pb] uniformly for all k
    for (int k = t; k < KPAD; k += 256) {
        unsigned pa, pb;
        if (k < 32)        { pa = (unsigned)k;        pb = 32u; }   // x * 1
        else if (k < 64)   { pa = (unsigned)(k - 32); pb = pa;  }   // x * x
        else if (k < HK)   { pa = (unsigned)idx_a[k - 64]; pb = (unsigned)idx_b[k - 64]; }
        else               { pa = 33u; pb = 33u; }                   // pad: 0*0
        s_lut[k] = pa | (pb << 16);
    }

    const int wv = t >> 6;              // wave id 0..3 -> m-tile (16 rows of B)
    const int lane = t & 63;
    const int lr = lane & 15;
    const int lq = lane >> 4;
    const int row = wv * 16 + lr;       // this lane's feat row
    const int wo = t & 31;              // weight staging: o
    const int wkg = t >> 5;             // weight staging: k-subgroup 0..7

    const float* wbase = w + (size_t)(c * NH + i) * HK * NH;

    // ---- prologue: load + convert + store weight chunk 0 into buffer 0
    float pv[8];
    #pragma unroll
    for (int r = 0; r < 8; ++r)
        pv[r] = wbase[(size_t)(wkg * 8 + r) * NH + wo];   // k<64, no guard
    {
        bf16x8 wv8;
        #pragma unroll
        for (int r = 0; r < 8; ++r) wv8[r] = (__bf16)pv[r];
        *(bf16x8*)&s_wT[0][wo][wkg * 8] = wv8;
    }
    __syncthreads();   // covers s_x, s_lut, s_wT[0]

    f32x4 acc0 = {0.f, 0.f, 0.f, 0.f};
    f32x4 acc1 = {0.f, 0.f, 0.f, 0.f};

    for (int ch = 0; ch < 9; ++ch) {
        const int k0 = ch * 64;
        const int buf = ch & 1;

        // ---- issue prefetch of next weight chunk (stays in flight over MFMA)
        if (ch < 8) {
            const int kb = k0 + 64 + wkg * 8;
            #pragma unroll
            for (int r = 0; r < 8; ++r) {
                const int k = kb + r;
                pv[r] = (k < HK) ? wbase[(size_t)k * NH + wo] : 0.0f;
            }
        }

        // ---- compute: A-fragments in registers, B from LDS, 4 MFMAs
        #pragma unroll
        for (int ks = 0; ks < 2; ++ks) {
            const uint4* lp = (const uint4*)&s_lut[k0 + ks * 32 + lq * 8];
            const uint4 L0 = lp[0], L1 = lp[1];
            const unsigned pr[8] = {L0.x, L0.y, L0.z, L0.w, L1.x, L1.y, L1.z, L1.w};
            bf16x8 a;
            #pragma unroll
            for (int j = 0; j < 8; ++j) {
                const float p = s_x[row][pr[j] & 0xffffu] * s_x[row][pr[j] >> 16];
                a[j] = (__bf16)p;
            }
            bf16x8 b0 = *(const bf16x8*)&s_wT[buf][lr][ks * 32 + lq * 8];
            bf16x8 b1 = *(const bf16x8*)&s_wT[buf][16 + lr][ks * 32 + lq * 8];
            acc0 = __builtin_amdgcn_mfma_f32_16x16x32_bf16(a, b0, acc0, 0, 0, 0);
            acc1 = __builtin_amdgcn_mfma_f32_16x16x32_bf16(a, b1, acc1, 0, 0, 0);
        }

        // ---- convert prefetched chunk, write other buffer; ONE barrier/chunk
        if (ch < 8) {
            bf16x8 wv8;
            #pragma unroll
            for (int r = 0; r < 8; ++r) wv8[r] = (__bf16)pv[r];
            *(bf16x8*)&s_wT[buf ^ 1][wo][wkg * 8] = wv8;
        }
        __syncthreads();
    }

    // ---- epilogue: C/D layout col=lane&15, row=quad*4+reg (validated R1)
    #pragma unroll
    for (int r = 0; r < 4; ++r) {
        const int b = wv * 16 + lq * 4 + r;
        float* op = out + (((size_t)b * NC + c) * NH + i) * NH;
        op[lr] = acc0[r];
        op[16 + lr] = acc1[r];
    }
}

extern "C" void kernel_launch(void* const* d_in, const int* in_sizes, int n_in,
                              void* d_out, int out_size, void* d_ws, size_t ws_size,
                              hipStream_t stream) {
    const float* x = (const float*)d_in[0];
    const float* w = (const float*)d_in[1];
    const int* idx_a = (const int*)d_in[2];
    const int* idx_b = (const int*)d_in[3];
    float* out = (float*)d_out;
    hconv_kernel<<<dim3(NC * NH), dim3(256), 0, stream>>>(x, w, idx_a, idx_b, out);
}